// Round 12
// baseline (301.436 us; speedup 1.0000x reference)
//
#include <hip/hip_runtime.h>

#define N_NODES 100000
#define N_EDGES 3200000
#define F_IN 128
#define F_HID 128
#define F_OUT 32
#define CAP 96      // padded CSR capacity; P(Poisson(32) > 96) ~ 4e-20 per node

#define NBUCK 1563  // coarse buckets of 64 dst nodes: (100000+63)>>6
#define CAPB 2432   // per-bucket staging capacity: mean 2048 + 8.5 sigma

#define BK 16

typedef float f32x2 __attribute__((ext_vector_type(2)));

// pack two floats to bf16x2 (RNE)
__device__ inline unsigned pack_bf16(float a, float b) {
    unsigned ua = __float_as_uint(a);
    ua = (ua + 0x7fffu + ((ua >> 16) & 1u)) >> 16;
    unsigned ub = __float_as_uint(b);
    ub = (ub + 0x7fffu + ((ub >> 16) & 1u)) >> 16;
    return ua | (ub << 16);
}
__device__ inline float lo16(unsigned u) { return __uint_as_float(u << 16); }
__device__ inline float hi16(unsigned u) { return __uint_as_float(u & 0xffff0000u); }

// ---------- P1: partition edges into coarse dst-buckets (LDS-binned) ----------
// 782 blocks (12 waves/CU), int4 edge loads; block covers 4096 edges.
// 4-byte staging record: [dst&63]:6 << 17 | src:17
__global__ __launch_bounds__(256) void k_part(const int* __restrict__ ei,
                                              int* __restrict__ gcur,
                                              unsigned* __restrict__ stage) {
    __shared__ int cnt[NBUCK];
    __shared__ int base[NBUCK];
    int tid = threadIdx.x;
    for (int i = tid; i < NBUCK; i += 256) cnt[i] = 0;
    __syncthreads();

    long e0 = (long)blockIdx.x * 4096;
    long rem = N_EDGES - e0;  // multiples of 1024 matter: 3.2M % 1024 == 0
    const int4* d4 = (const int4*)(ei + N_EDGES + e0);
    const int4* s4 = (const int4*)(ei + e0);
    int4 dc0, dc1, dc2, dc3;  // named registers (static indexing)

#define HIST(DC, I)                                                     \
    if ((I + 1) * 1024 <= rem) {                                        \
        DC = d4[I * 256 + tid];                                         \
        atomicAdd(&cnt[DC.x >> 6], 1); atomicAdd(&cnt[DC.y >> 6], 1);   \
        atomicAdd(&cnt[DC.z >> 6], 1); atomicAdd(&cnt[DC.w >> 6], 1);   \
    }
    HIST(dc0, 0) HIST(dc1, 1) HIST(dc2, 2) HIST(dc3, 3)
#undef HIST
    __syncthreads();
    for (int i = tid; i < NBUCK; i += 256) {
        base[i] = atomicAdd(&gcur[i], cnt[i]);
        cnt[i] = 0;
    }
    __syncthreads();

#define PLACE(D, S)                                                     \
    {                                                                   \
        int b_ = (D) >> 6;                                              \
        int pos_ = base[b_] + atomicAdd(&cnt[b_], 1);                   \
        if (pos_ < CAPB)                                                \
            stage[(size_t)b_ * CAPB + pos_] =                           \
                ((unsigned)((D) & 63) << 17) | (unsigned)(S);           \
    }
#define WR(DC, I)                                                       \
    if ((I + 1) * 1024 <= rem) {                                        \
        int4 sv = s4[I * 256 + tid];                                    \
        PLACE(DC.x, sv.x) PLACE(DC.y, sv.y)                             \
        PLACE(DC.z, sv.z) PLACE(DC.w, sv.w)                             \
    }
    WR(dc0, 0) WR(dc1, 1) WR(dc2, 2) WR(dc3, 3)
#undef WR
#undef PLACE
}

// ---------- P2 fused: bucket -> padded CSR + deg/dinv + GEMM1 tile ----------
// Bucket b's 64 dst nodes ARE gemm1's BM=64 tile b. CSR phase (memory/LDS-atomic)
// pipelines against other blocks' GEMM phase (VALU) on the same CU.
__global__ __launch_bounds__(256) void k_csr_gemm1(const unsigned* __restrict__ stage,
                                                   const int* __restrict__ gcur,
                                                   int* __restrict__ csr,
                                                   int* __restrict__ deg,
                                                   float* __restrict__ dinv,
                                                   const float* __restrict__ x,
                                                   const float* __restrict__ W1,
                                                   unsigned* __restrict__ g1u) {
    __shared__ int cnt[64];
    __shared__ float dv[64];
    __shared__ float xT[BK][68];     // transposed x tile [k][m]
    __shared__ float wt[BK][F_HID];  // W tile [k][j]

    int b = blockIdx.x;
    int tid = threadIdx.x;
    if (tid < 64) cnt[tid] = 0;
    __syncthreads();

    // ---- CSR build for nodes [b*64, b*64+64) ----
    int d0 = b << 6;
    int m = gcur[b];
    if (m > CAPB) m = CAPB;
    const unsigned* sp = stage + (size_t)b * CAPB;
    for (int i = tid; i < m; i += 256) {
        unsigned rec = __builtin_nontemporal_load(sp + i);
        int s = (int)(rec & 0x1ffffu);
        int dl = (int)(rec >> 17);
        int pos = atomicAdd(&cnt[dl], 1);
        if (pos < CAP) csr[(size_t)(d0 + dl) * CAP + pos] = s;
    }
    __syncthreads();
    if (tid < 64) {
        int dd = d0 + tid;
        float di = 0.f;
        if (dd < N_NODES) {
            int dg = cnt[tid];
            deg[dd] = dg;
            di = rsqrtf((float)(dg + 1));  // +1 self-loop
            dinv[dd] = di;
        }
        dv[tid] = di;
    }
    // (dv visibility covered by the first __syncthreads in the k-loop)

    // ---- GEMM1 64x128 tile: g1[d0..d0+64) = bf16( (x @ W1) * dv ) ----
    int rg = tid >> 4;
    int cg = tid & 15;
    int r0 = rg * 4;
    int c0 = cg * 8;

    int lr = tid >> 2;
    int lk = (tid & 3) * 4;
    int gr = d0 + lr;
    int grc = gr < N_NODES ? gr : N_NODES - 1;
    const float* xrow = x + (size_t)grc * F_IN + lk;

    float acc[4][8];
#pragma unroll
    for (int i = 0; i < 4; ++i)
#pragma unroll
        for (int j = 0; j < 8; ++j) acc[i][j] = 0.f;

    for (int k0 = 0; k0 < F_IN; k0 += BK) {
        float4 v = *(const float4*)(xrow + k0);
        const float4* w4 = (const float4*)(W1 + (size_t)k0 * F_HID);
        float4 wv0 = w4[tid];
        float4 wv1 = w4[tid + 256];

        xT[lk + 0][lr] = v.x;
        xT[lk + 1][lr] = v.y;
        xT[lk + 2][lr] = v.z;
        xT[lk + 3][lr] = v.w;
        ((float4*)wt)[tid] = wv0;
        ((float4*)wt)[tid + 256] = wv1;
        __syncthreads();

#pragma unroll
        for (int k = 0; k < BK; ++k) {
            float a[4], bb[8];
            *(float4*)a = *(const float4*)&xT[k][r0];
            *(float4*)(bb + 0) = *(const float4*)&wt[k][c0];
            *(float4*)(bb + 4) = *(const float4*)&wt[k][c0 + 4];
#pragma unroll
            for (int i = 0; i < 4; ++i)
#pragma unroll
                for (int j = 0; j < 8; ++j)
                    acc[i][j] = fmaf(a[i], bb[j], acc[i][j]);
        }
        __syncthreads();
    }

#pragma unroll
    for (int i = 0; i < 4; ++i) {
        int n = d0 + r0 + i;
        if (n < N_NODES) {
            float s = dv[r0 + i];
            uint4 o;
            o.x = pack_bf16(acc[i][0] * s, acc[i][1] * s);
            o.y = pack_bf16(acc[i][2] * s, acc[i][3] * s);
            o.z = pack_bf16(acc[i][4] * s, acc[i][5] * s);
            o.w = pack_bf16(acc[i][6] * s, acc[i][7] * s);
            *(uint4*)(g1u + (size_t)n * 64 + (c0 >> 1)) = o;
        }
    }
}

// ------- pull layer1 + relu/bias + GEMM2 fused: 16 nodes/block, 4 nodes/wave -----
// (frozen: R10 form — gather at its structural floor)
__global__ __launch_bounds__(256) void k_pull1_gemm2(const int* __restrict__ csr,
                                                     const int* __restrict__ deg_i,
                                                     const unsigned* __restrict__ g1u,
                                                     const float* __restrict__ dinv,
                                                     const float* __restrict__ b1,
                                                     const float* __restrict__ W2,
                                                     unsigned* __restrict__ g2u) {
    __shared__ float w2l[F_HID * F_OUT];   // [k][j], 16 KB
    __shared__ unsigned alu[16][64];       // packed bf16x2 activations, 4 KB
    {
        const float4* w4 = (const float4*)W2;
        float4* wl4 = (float4*)w2l;
#pragma unroll
        for (int i = 0; i < 4; ++i)
            wl4[threadIdx.x + i * 256] = w4[threadIdx.x + i * 256];
    }
    int lane = threadIdx.x & 63;
    int wv = threadIdx.x >> 6;
    int nb4 = __builtin_amdgcn_readfirstlane(blockIdx.x * 16 + wv * 4);

    int4 deg4 = *(const int4*)(deg_i + nb4);
    float4 di4 = *(const float4*)(dinv + nb4);
    float2 bb = *(const float2*)(b1 + lane * 2);

#define GATHER(S, ACC)                                            \
    {                                                             \
        const unsigned* p = g1u + ((size_t)(unsigned)(S) << 6);   \
        unsigned v = p[lane];                                     \
        ACC += (f32x2){lo16(v), hi16(v)};                         \
    }

#pragma unroll
    for (int i = 0; i < 4; ++i) {
        int n = nb4 + i;  // uniform
        int deg = ((const int*)&deg4)[i];
        if (deg > CAP) deg = CAP;
        const int* crow = csr + (size_t)n * CAP;
        int sidx0 = (lane < deg) ? __builtin_nontemporal_load(crow + lane) : 0;

        unsigned us = g1u[(size_t)n * 64 + lane];  // self-loop
        f32x2 ac0 = (f32x2){lo16(us), hi16(us)};
        f32x2 ac1 = (f32x2){0.f, 0.f}, ac2 = ac1, ac3 = ac1;

        int m1 = deg < 64 ? deg : 64;  // uniform
        int j = 0;
        for (; j + 3 < m1; j += 4) {
            int s0 = __builtin_amdgcn_readlane(sidx0, j);
            int s1 = __builtin_amdgcn_readlane(sidx0, j + 1);
            int s2 = __builtin_amdgcn_readlane(sidx0, j + 2);
            int s3 = __builtin_amdgcn_readlane(sidx0, j + 3);
            GATHER(s0, ac0) GATHER(s1, ac1) GATHER(s2, ac2) GATHER(s3, ac3)
        }
        for (; j < m1; ++j) {
            int s0 = __builtin_amdgcn_readlane(sidx0, j);
            GATHER(s0, ac0)
        }
        if (deg > 64) {  // uniform cold path, P ~ 4e-8
            int sidx1 = __builtin_nontemporal_load(crow + 64 + (lane & 31));
            int m2 = deg - 64;
            for (j = 0; j < m2; ++j) {
                int s0 = __builtin_amdgcn_readlane(sidx1, j);
                GATHER(s0, ac0)
            }
        }
        f32x2 a = (ac0 + ac1) + (ac2 + ac3);
        float di = ((const float*)&di4)[i];
        float a0 = fmaxf(fmaf(di, a.x, bb.x), 0.f);
        float a1 = fmaxf(fmaf(di, a.y, bb.y), 0.f);
        alu[wv * 4 + i][lane] = pack_bf16(a0, a1);
    }
#undef GATHER
    __syncthreads();

    // GEMM2: lane (jj = out col, kh = k half); 1 W2 read feeds 4 nodes
    int jj = lane & 31, kh = lane >> 5;
    f32x2 s0 = {0.f, 0.f}, s1 = s0, s2 = s0, s3 = s0;
#pragma unroll 4
    for (int k2 = 0; k2 < 32; ++k2) {
        int k = kh * 64 + k2 * 2;
        f32x2 w = (f32x2){w2l[k * F_OUT + jj], w2l[(k + 1) * F_OUT + jj]};
        int ki = kh * 32 + k2;
        unsigned p0 = alu[wv * 4 + 0][ki];
        unsigned p1 = alu[wv * 4 + 1][ki];
        unsigned p2 = alu[wv * 4 + 2][ki];
        unsigned p3 = alu[wv * 4 + 3][ki];
        s0 += (f32x2){lo16(p0), hi16(p0)} * w;
        s1 += (f32x2){lo16(p1), hi16(p1)} * w;
        s2 += (f32x2){lo16(p2), hi16(p2)} * w;
        s3 += (f32x2){lo16(p3), hi16(p3)} * w;
    }
    float r0 = s0.x + s0.y, r1 = s1.x + s1.y, r2 = s2.x + s2.y, r3 = s3.x + s3.y;
    r0 += __shfl_xor(r0, 32); r1 += __shfl_xor(r1, 32);
    r2 += __shfl_xor(r2, 32); r3 += __shfl_xor(r3, 32);
    r0 *= ((const float*)&di4)[0]; r1 *= ((const float*)&di4)[1];
    r2 *= ((const float*)&di4)[2]; r3 *= ((const float*)&di4)[3];

    int fl16 = lane & 15;
    float sa0 = __shfl(r0, fl16 * 2), sb0 = __shfl(r0, fl16 * 2 + 1);
    float sa1 = __shfl(r1, fl16 * 2), sb1 = __shfl(r1, fl16 * 2 + 1);
    float sa2 = __shfl(r2, fl16 * 2), sb2 = __shfl(r2, fl16 * 2 + 1);
    float sa3 = __shfl(r3, fl16 * 2), sb3 = __shfl(r3, fl16 * 2 + 1);
    if (lane < 16) {
        g2u[(size_t)(nb4 + 0) * 16 + fl16] = pack_bf16(sa0, sb0);
        g2u[(size_t)(nb4 + 1) * 16 + fl16] = pack_bf16(sa1, sb1);
        g2u[(size_t)(nb4 + 2) * 16 + fl16] = pack_bf16(sa2, sb2);
        g2u[(size_t)(nb4 + 3) * 16 + fl16] = pack_bf16(sa3, sb3);
    }
}

// ------- pull layer2 + bias, quarter-wave (16 lanes) per dst node -------
__global__ __launch_bounds__(256) void k_pull2(const int* __restrict__ csr,
                                               const int* __restrict__ deg_i,
                                               const unsigned* __restrict__ g2u,
                                               const float* __restrict__ dinv,
                                               const float* __restrict__ b2,
                                               float* __restrict__ out) {
    int lane = threadIdx.x & 63;
    int wv = threadIdx.x >> 6;
    int qw = lane >> 4, fl = lane & 15;
    int n = blockIdx.x * 16 + wv * 4 + qw;

    unsigned u0 = g2u[(size_t)n * 16 + fl];  // self-loop
    float a0x = lo16(u0), a0y = hi16(u0);
    float a1x = 0.f, a1y = 0.f, a2x = 0.f, a2y = 0.f, a3x = 0.f, a3y = 0.f;
    int deg = deg_i[n];
    if (deg > CAP) deg = CAP;
    const int* crow = csr + (size_t)n * CAP;
    for (int e0 = 0; e0 < deg; e0 += 16) {
        int rem = deg - e0;
        int m = rem < 16 ? rem : 16;
        int sidx = (fl < m) ? __builtin_nontemporal_load(crow + e0 + fl) : 0;
        int j = 0;
        for (; j + 3 < m; j += 4) {
            int s0 = __shfl(sidx, j, 16);
            int s1 = __shfl(sidx, j + 1, 16);
            int s2 = __shfl(sidx, j + 2, 16);
            int s3 = __shfl(sidx, j + 3, 16);
            unsigned v0 = g2u[(unsigned)s0 * 16u + fl];
            unsigned v1 = g2u[(unsigned)s1 * 16u + fl];
            unsigned v2 = g2u[(unsigned)s2 * 16u + fl];
            unsigned v3 = g2u[(unsigned)s3 * 16u + fl];
            a0x += lo16(v0); a0y += hi16(v0);
            a1x += lo16(v1); a1y += hi16(v1);
            a2x += lo16(v2); a2y += hi16(v2);
            a3x += lo16(v3); a3y += hi16(v3);
        }
        for (; j < m; ++j) {
            int s0 = __shfl(sidx, j, 16);
            unsigned v0 = g2u[(unsigned)s0 * 16u + fl];
            a0x += lo16(v0); a0y += hi16(v0);
        }
    }
    float ax = (a0x + a1x) + (a2x + a3x);
    float ay = (a0y + a1y) + (a2y + a3y);

    float di = dinv[n];
    float2 bb = *(const float2*)(b2 + fl * 2);
    f32x2 o;
    o.x = fmaf(di, ax, bb.x);
    o.y = fmaf(di, ay, bb.y);
    __builtin_nontemporal_store(o, (f32x2*)(out + (size_t)n * F_OUT + fl * 2));
}

extern "C" void kernel_launch(void* const* d_in, const int* in_sizes, int n_in,
                              void* d_out, int out_size, void* d_ws, size_t ws_size,
                              hipStream_t stream) {
    const float* x  = (const float*)d_in[0];
    const int*   ei = (const int*)d_in[1];
    const float* W1 = (const float*)d_in[2];
    const float* b1 = (const float*)d_in[3];
    const float* W2 = (const float*)d_in[4];
    const float* b2 = (const float*)d_in[5];
    float* out = (float*)d_out;

    char* ws = (char*)d_ws;
    int*      deg   = (int*)(ws);                    // 400 KB (pad 512 KB)
    float*    dinv  = (float*)(ws + 524288);         // 400 KB (pad 512 KB)
    int*      gcur  = (int*)(ws + 1048576);          // 6.3 KB (pad 512 KB)
    int*      csr   = (int*)(ws + 1572864);          // 38.4 MB (ends 39,972,864)
    unsigned* stage = (unsigned*)(ws + 40000000);    // 1563*2432*4 = 15.2 MB
    unsigned* g1u   = (unsigned*)(ws + 55204864);    // 25.6 MB
    unsigned* g2u   = (unsigned*)(ws + 80804864);    // 6.4 MB (end ~87.2 MB)

    (void)hipMemsetAsync(gcur, 0, NBUCK * sizeof(int), stream);
    k_part<<<(N_EDGES + 4095) / 4096, 256, 0, stream>>>(ei, gcur, stage);
    k_csr_gemm1<<<NBUCK, 256, 0, stream>>>(stage, gcur, csr, deg, dinv, x, W1, g1u);

    k_pull1_gemm2<<<N_NODES / 16, 256, 0, stream>>>(csr, deg, g1u, dinv, b1, W2, g2u);
    k_pull2<<<N_NODES / 16, 256, 0, stream>>>(csr, deg, g2u, dinv, b2, out);
}

// Round 13
// 293.255 us; speedup vs baseline: 1.0279x; 1.0279x over previous
//
#include <hip/hip_runtime.h>

#define N_NODES 100000
#define N_EDGES 3200000
#define F_IN 128
#define F_HID 128
#define F_OUT 32
#define CAP 96      // padded CSR capacity; P(Poisson(32) > 96) ~ 4e-20 per node

#define NBUCK 391   // coarse buckets of 256 dst nodes
#define CAPB 8960   // per-bucket staging capacity
#define EPT 32      // edges per thread in k_part

#define BM 128
#define BK 16

typedef float f32x2 __attribute__((ext_vector_type(2)));

// pack two floats to bf16x2 (RNE)
__device__ inline unsigned pack_bf16(float a, float b) {
    unsigned ua = __float_as_uint(a);
    ua = (ua + 0x7fffu + ((ua >> 16) & 1u)) >> 16;
    unsigned ub = __float_as_uint(b);
    ub = (ub + 0x7fffu + ((ub >> 16) & 1u)) >> 16;
    return ua | (ub << 16);
}
__device__ inline float lo16(unsigned u) { return __uint_as_float(u << 16); }
__device__ inline float hi16(unsigned u) { return __uint_as_float(u & 0xffff0000u); }

// ---------- P1: partition edges into coarse dst-buckets (LDS-binned) ----------
// 4-byte staging record: [dst&255]:8 << 17 | src:17
__global__ __launch_bounds__(256) void k_part(const int* __restrict__ ei,
                                              int* __restrict__ gcur,
                                              unsigned* __restrict__ stage) {
    __shared__ int cnt[NBUCK];
    __shared__ int base[NBUCK];
    int tid = threadIdx.x;
    for (int i = tid; i < NBUCK; i += 256) cnt[i] = 0;
    __syncthreads();

    long e0 = (long)blockIdx.x * (256 * EPT);
#pragma unroll 4
    for (int i = 0; i < EPT; ++i) {
        long e = e0 + i * 256 + tid;
        if (e < N_EDGES) atomicAdd(&cnt[ei[N_EDGES + e] >> 8], 1);
    }
    __syncthreads();
    for (int i = tid; i < NBUCK; i += 256) {
        base[i] = atomicAdd(&gcur[i], cnt[i]);
        cnt[i] = 0;
    }
    __syncthreads();
#pragma unroll 4
    for (int i = 0; i < EPT; ++i) {
        long e = e0 + i * 256 + tid;
        if (e < N_EDGES) {
            int s = ei[e];
            int d = ei[N_EDGES + e];
            int b = d >> 8;
            int pos = base[b] + atomicAdd(&cnt[b], 1);
            if (pos < CAPB)
                stage[(size_t)b * CAPB + pos] = ((unsigned)(d & 255) << 17) | (unsigned)s;
        }
    }
}

// ---------- P2: bucket -> padded CSR; emits degree and dinv ----------
__global__ __launch_bounds__(256) void k_csr(const unsigned* __restrict__ stage,
                                             const int* __restrict__ gcur,
                                             int* __restrict__ csr,
                                             int* __restrict__ deg,
                                             float* __restrict__ dinv) {
    __shared__ int cnt[256];
    int b = blockIdx.x;
    int tid = threadIdx.x;
    cnt[tid] = 0;
    __syncthreads();

    int d0 = b << 8;
    int m = gcur[b];
    if (m > CAPB) m = CAPB;
    const unsigned* sp = stage + (size_t)b * CAPB;
    for (int i = tid; i < m; i += 256) {
        unsigned rec = __builtin_nontemporal_load(sp + i);
        int s = (int)(rec & 0x1ffffu);
        int dl = (int)(rec >> 17);
        int pos = atomicAdd(&cnt[dl], 1);
        if (pos < CAP) csr[(size_t)(d0 + dl) * CAP + pos] = s;
    }
    __syncthreads();
    int dd = d0 + tid;
    if (dd < N_NODES) {
        int dg = cnt[tid];
        deg[dd] = dg;
        dinv[dd] = rsqrtf((float)(dg + 1));  // +1 self-loop
    }
}

// ------- GEMM1: g1 = bf16( (x @ W1) * dinv[row] ), BM=128, 8x8 acc -------
__global__ __launch_bounds__(256) void k_gemm1(const float* __restrict__ x,
                                               const float* __restrict__ W1,
                                               const float* __restrict__ dinv,
                                               unsigned* __restrict__ g1u) {
    __shared__ float xT[BK][BM + 8];   // [k][m], 16x136 = 8.7 KB
    __shared__ float wt[BK][F_HID];    // [k][j], 8 KB

    int tid = threadIdx.x;
    int m0 = blockIdx.x * BM;

    int rg = tid >> 4;      // 0..15
    int cg = tid & 15;      // 0..15
    int r0 = rg * 8;
    int c0 = cg * 8;

    int lr = tid >> 1;            // local row 0..127
    int lk = (tid & 1) * 8;       // k-octet 0 or 8
    int gr = m0 + lr;
    int grc = gr < N_NODES ? gr : N_NODES - 1;
    const float* xrow = x + (size_t)grc * F_IN + lk;

    float acc[8][8];
#pragma unroll
    for (int i = 0; i < 8; ++i)
#pragma unroll
        for (int j = 0; j < 8; ++j) acc[i][j] = 0.f;

    for (int k0 = 0; k0 < F_IN; k0 += BK) {
        float4 v0 = *(const float4*)(xrow + k0);
        float4 v1 = *(const float4*)(xrow + k0 + 4);
        const float4* w4 = (const float4*)(W1 + (size_t)k0 * F_HID);
        float4 wv0 = w4[tid];
        float4 wv1 = w4[tid + 256];

        xT[lk + 0][lr] = v0.x; xT[lk + 1][lr] = v0.y;
        xT[lk + 2][lr] = v0.z; xT[lk + 3][lr] = v0.w;
        xT[lk + 4][lr] = v1.x; xT[lk + 5][lr] = v1.y;
        xT[lk + 6][lr] = v1.z; xT[lk + 7][lr] = v1.w;
        ((float4*)wt)[tid] = wv0;
        ((float4*)wt)[tid + 256] = wv1;
        __syncthreads();

#pragma unroll
        for (int k = 0; k < BK; ++k) {
            float a[8], b[8];
            *(float4*)(a + 0) = *(const float4*)&xT[k][r0];
            *(float4*)(a + 4) = *(const float4*)&xT[k][r0 + 4];
            *(float4*)(b + 0) = *(const float4*)&wt[k][c0];
            *(float4*)(b + 4) = *(const float4*)&wt[k][c0 + 4];
#pragma unroll
            for (int i = 0; i < 8; ++i)
#pragma unroll
                for (int j = 0; j < 8; ++j)
                    acc[i][j] = fmaf(a[i], b[j], acc[i][j]);
        }
        __syncthreads();
    }

#pragma unroll
    for (int i = 0; i < 8; ++i) {
        int n = m0 + r0 + i;
        if (n < N_NODES) {
            float s = dinv[n];
            uint4 o;
            o.x = pack_bf16(acc[i][0] * s, acc[i][1] * s);
            o.y = pack_bf16(acc[i][2] * s, acc[i][3] * s);
            o.z = pack_bf16(acc[i][4] * s, acc[i][5] * s);
            o.w = pack_bf16(acc[i][6] * s, acc[i][7] * s);
            *(uint4*)(g1u + (size_t)n * 64 + (c0 >> 1)) = o;
        }
    }
}

// ------- pull layer1 + relu/bias + GEMM2 fused: 16 nodes/block, 4 nodes/wave -----
// gather: scalar-pipe, 4-acc 4-deep + masked preload (structural floor)
// epilogue: one W2 LDS read feeds 4 nodes; al packed bf16x2 in LDS
__global__ __launch_bounds__(256) void k_pull1_gemm2(const int* __restrict__ csr,
                                                     const int* __restrict__ deg_i,
                                                     const unsigned* __restrict__ g1u,
                                                     const float* __restrict__ dinv,
                                                     const float* __restrict__ b1,
                                                     const float* __restrict__ W2,
                                                     unsigned* __restrict__ g2u) {
    __shared__ float w2l[F_HID * F_OUT];   // [k][j], 16 KB
    __shared__ unsigned alu[16][64];       // packed bf16x2 activations, 4 KB
    {
        const float4* w4 = (const float4*)W2;
        float4* wl4 = (float4*)w2l;
#pragma unroll
        for (int i = 0; i < 4; ++i)
            wl4[threadIdx.x + i * 256] = w4[threadIdx.x + i * 256];
    }
    int lane = threadIdx.x & 63;
    int wv = threadIdx.x >> 6;
    int nb4 = __builtin_amdgcn_readfirstlane(blockIdx.x * 16 + wv * 4);

    int4 deg4 = *(const int4*)(deg_i + nb4);    // uniform -> s_load_dwordx4
    float4 di4 = *(const float4*)(dinv + nb4);  // uniform -> s_load_dwordx4
    float2 bb = *(const float2*)(b1 + lane * 2);

#define GATHER(S, ACC)                                            \
    {                                                             \
        const unsigned* p = g1u + ((size_t)(unsigned)(S) << 6);   \
        unsigned v = p[lane];                                     \
        ACC += (f32x2){lo16(v), hi16(v)};                         \
    }

#pragma unroll
    for (int i = 0; i < 4; ++i) {
        int n = nb4 + i;  // uniform
        int deg = ((const int*)&deg4)[i];
        if (deg > CAP) deg = CAP;
        const int* crow = csr + (size_t)n * CAP;
        int sidx0 = (lane < deg) ? __builtin_nontemporal_load(crow + lane) : 0;

        unsigned us = g1u[(size_t)n * 64 + lane];  // self-loop
        f32x2 ac0 = (f32x2){lo16(us), hi16(us)};
        f32x2 ac1 = (f32x2){0.f, 0.f}, ac2 = ac1, ac3 = ac1;

        int m1 = deg < 64 ? deg : 64;  // uniform
        int j = 0;
        for (; j + 3 < m1; j += 4) {
            int s0 = __builtin_amdgcn_readlane(sidx0, j);
            int s1 = __builtin_amdgcn_readlane(sidx0, j + 1);
            int s2 = __builtin_amdgcn_readlane(sidx0, j + 2);
            int s3 = __builtin_amdgcn_readlane(sidx0, j + 3);
            GATHER(s0, ac0) GATHER(s1, ac1) GATHER(s2, ac2) GATHER(s3, ac3)
        }
        for (; j < m1; ++j) {
            int s0 = __builtin_amdgcn_readlane(sidx0, j);
            GATHER(s0, ac0)
        }
        if (deg > 64) {  // uniform cold path, P ~ 4e-8
            int sidx1 = __builtin_nontemporal_load(crow + 64 + (lane & 31));
            int m2 = deg - 64;
            for (j = 0; j < m2; ++j) {
                int s0 = __builtin_amdgcn_readlane(sidx1, j);
                GATHER(s0, ac0)
            }
        }
        f32x2 a = (ac0 + ac1) + (ac2 + ac3);
        float di = ((const float*)&di4)[i];
        float a0 = fmaxf(fmaf(di, a.x, bb.x), 0.f);
        float a1 = fmaxf(fmaf(di, a.y, bb.y), 0.f);
        alu[wv * 4 + i][lane] = pack_bf16(a0, a1);
    }
#undef GATHER
    __syncthreads();

    // GEMM2: lane (jj = out col, kh = k half); 1 W2 read feeds 4 nodes
    int jj = lane & 31, kh = lane >> 5;
    f32x2 s0 = {0.f, 0.f}, s1 = s0, s2 = s0, s3 = s0;
#pragma unroll 4
    for (int k2 = 0; k2 < 32; ++k2) {
        int k = kh * 64 + k2 * 2;
        f32x2 w = (f32x2){w2l[k * F_OUT + jj], w2l[(k + 1) * F_OUT + jj]};
        int ki = kh * 32 + k2;
        unsigned p0 = alu[wv * 4 + 0][ki];
        unsigned p1 = alu[wv * 4 + 1][ki];
        unsigned p2 = alu[wv * 4 + 2][ki];
        unsigned p3 = alu[wv * 4 + 3][ki];
        s0 += (f32x2){lo16(p0), hi16(p0)} * w;
        s1 += (f32x2){lo16(p1), hi16(p1)} * w;
        s2 += (f32x2){lo16(p2), hi16(p2)} * w;
        s3 += (f32x2){lo16(p3), hi16(p3)} * w;
    }
    float r0 = s0.x + s0.y, r1 = s1.x + s1.y, r2 = s2.x + s2.y, r3 = s3.x + s3.y;
    r0 += __shfl_xor(r0, 32); r1 += __shfl_xor(r1, 32);
    r2 += __shfl_xor(r2, 32); r3 += __shfl_xor(r3, 32);
    r0 *= ((const float*)&di4)[0]; r1 *= ((const float*)&di4)[1];
    r2 *= ((const float*)&di4)[2]; r3 *= ((const float*)&di4)[3];

    int fl16 = lane & 15;
    float sa0 = __shfl(r0, fl16 * 2), sb0 = __shfl(r0, fl16 * 2 + 1);
    float sa1 = __shfl(r1, fl16 * 2), sb1 = __shfl(r1, fl16 * 2 + 1);
    float sa2 = __shfl(r2, fl16 * 2), sb2 = __shfl(r2, fl16 * 2 + 1);
    float sa3 = __shfl(r3, fl16 * 2), sb3 = __shfl(r3, fl16 * 2 + 1);
    if (lane < 16) {
        g2u[(size_t)(nb4 + 0) * 16 + fl16] = pack_bf16(sa0, sb0);
        g2u[(size_t)(nb4 + 1) * 16 + fl16] = pack_bf16(sa1, sb1);
        g2u[(size_t)(nb4 + 2) * 16 + fl16] = pack_bf16(sa2, sb2);
        g2u[(size_t)(nb4 + 3) * 16 + fl16] = pack_bf16(sa3, sb3);
    }
}

// ------- pull layer2 + bias, quarter-wave (16 lanes) per dst node -------
__global__ __launch_bounds__(256) void k_pull2(const int* __restrict__ csr,
                                               const int* __restrict__ deg_i,
                                               const unsigned* __restrict__ g2u,
                                               const float* __restrict__ dinv,
                                               const float* __restrict__ b2,
                                               float* __restrict__ out) {
    int lane = threadIdx.x & 63;
    int wv = threadIdx.x >> 6;
    int qw = lane >> 4, fl = lane & 15;
    int n = blockIdx.x * 16 + wv * 4 + qw;

    unsigned u0 = g2u[(size_t)n * 16 + fl];  // self-loop
    float a0x = lo16(u0), a0y = hi16(u0);
    float a1x = 0.f, a1y = 0.f, a2x = 0.f, a2y = 0.f, a3x = 0.f, a3y = 0.f;
    int deg = deg_i[n];
    if (deg > CAP) deg = CAP;
    const int* crow = csr + (size_t)n * CAP;
    for (int e0 = 0; e0 < deg; e0 += 16) {
        int rem = deg - e0;
        int m = rem < 16 ? rem : 16;
        int sidx = (fl < m) ? __builtin_nontemporal_load(crow + e0 + fl) : 0;
        int j = 0;
        for (; j + 3 < m; j += 4) {
            int s0 = __shfl(sidx, j, 16);
            int s1 = __shfl(sidx, j + 1, 16);
            int s2 = __shfl(sidx, j + 2, 16);
            int s3 = __shfl(sidx, j + 3, 16);
            unsigned v0 = g2u[(unsigned)s0 * 16u + fl];
            unsigned v1 = g2u[(unsigned)s1 * 16u + fl];
            unsigned v2 = g2u[(unsigned)s2 * 16u + fl];
            unsigned v3 = g2u[(unsigned)s3 * 16u + fl];
            a0x += lo16(v0); a0y += hi16(v0);
            a1x += lo16(v1); a1y += hi16(v1);
            a2x += lo16(v2); a2y += hi16(v2);
            a3x += lo16(v3); a3y += hi16(v3);
        }
        for (; j < m; ++j) {
            int s0 = __shfl(sidx, j, 16);
            unsigned v0 = g2u[(unsigned)s0 * 16u + fl];
            a0x += lo16(v0); a0y += hi16(v0);
        }
    }
    float ax = (a0x + a1x) + (a2x + a3x);
    float ay = (a0y + a1y) + (a2y + a3y);

    float di = dinv[n];
    float2 bb = *(const float2*)(b2 + fl * 2);
    f32x2 o;
    o.x = fmaf(di, ax, bb.x);
    o.y = fmaf(di, ay, bb.y);
    __builtin_nontemporal_store(o, (f32x2*)(out + (size_t)n * F_OUT + fl * 2));
}

extern "C" void kernel_launch(void* const* d_in, const int* in_sizes, int n_in,
                              void* d_out, int out_size, void* d_ws, size_t ws_size,
                              hipStream_t stream) {
    const float* x  = (const float*)d_in[0];
    const int*   ei = (const int*)d_in[1];
    const float* W1 = (const float*)d_in[2];
    const float* b1 = (const float*)d_in[3];
    const float* W2 = (const float*)d_in[4];
    const float* b2 = (const float*)d_in[5];
    float* out = (float*)d_out;

    char* ws = (char*)d_ws;
    int*      deg   = (int*)(ws);                    // 400 KB (pad 512 KB)
    float*    dinv  = (float*)(ws + 524288);         // 400 KB (pad 512 KB)
    int*      gcur  = (int*)(ws + 1048576);          // 4 KB (pad 512 KB)
    int*      csr   = (int*)(ws + 1572864);          // 38.4 MB
    unsigned* stage = (unsigned*)(ws + 40000000);    // 14.0 MB (4B records)
    unsigned* g1u   = (unsigned*)(ws + 54016000);    // 25.6 MB
    unsigned* g2u   = (unsigned*)(ws + 79616000);    // 6.4 MB (end ~86 MB)

    (void)hipMemsetAsync(gcur, 0, 4096, stream);
    k_part<<<(N_EDGES + 256 * EPT - 1) / (256 * EPT), 256, 0, stream>>>(ei, gcur, stage);
    k_csr<<<NBUCK, 256, 0, stream>>>(stage, gcur, csr, deg, dinv);

    k_gemm1<<<(N_NODES + BM - 1) / BM, 256, 0, stream>>>(x, W1, dinv, g1u);

    k_pull1_gemm2<<<N_NODES / 16, 256, 0, stream>>>(csr, deg, g1u, dinv, b1, W2, g2u);
    k_pull2<<<N_NODES / 16, 256, 0, stream>>>(csr, deg, g2u, dinv, b2, out);
}